// Round 10
// baseline (263.495 us; speedup 1.0000x reference)
//
#include <hip/hip_runtime.h>
#include <hip/hip_bf16.h>

#define B_   4
#define NX_  1024
#define NC_  2048
#define C_   1024
#define H_   16
#define DH_  64

typedef __attribute__((ext_vector_type(8))) __bf16 bf16x8;
typedef __attribute__((ext_vector_type(4))) float  f32x4;

// RNE float->bf16 (inputs finite)
static __device__ __forceinline__ unsigned short f2bf(float f) {
    unsigned int u = __float_as_uint(f);
    u += 0x7fffu + ((u >> 16) & 1u);
    return (unsigned short)(u >> 16);
}

// pack 2 floats -> 2 bf16 (round-half-up)
static __device__ __forceinline__ unsigned int pk2(float lo, float hi) {
    unsigned int a = __float_as_uint(lo) + 0x8000u;
    unsigned int b = __float_as_uint(hi) + 0x8000u;
    return __builtin_amdgcn_perm(b, a, 0x07060302);   // {b.hi16, a.hi16}
}

static __device__ __forceinline__ bf16x8 ldfrag(const unsigned short* p) {
    union { uint4 u; bf16x8 b; } cv;
    cv.u = *reinterpret_cast<const uint4*>(p);
    return cv.b;
}

// ---------------- merged converts: x, w_qkv, w_proj, cache_k (flat) + cache_v (transpose) ----------------
__global__ __launch_bounds__(256) void cvt_all_kernel(
    const float* __restrict__ x,  const float* __restrict__ wq,
    const float* __restrict__ wp, const float* __restrict__ ck,
    const float* __restrict__ cv_,
    unsigned short* __restrict__ xbf,  unsigned short* __restrict__ wqbf,
    unsigned short* __restrict__ wpbf, unsigned short* __restrict__ kfb,
    unsigned short* __restrict__ vt) {
    int blk = blockIdx.x;
    if (blk < 16384) {
        const float* src; unsigned short* dst; int i;
        if (blk < 4096)      { src = x;  dst = xbf;  i = blk; }
        else if (blk < 7168) { src = wq; dst = wqbf; i = blk - 4096; }
        else if (blk < 8192) { src = wp; dst = wpbf; i = blk - 7168; }
        else                 { src = ck; dst = kfb;  i = blk - 8192; }
        int idx = i * 256 + threadIdx.x;
        float4 f = reinterpret_cast<const float4*>(src)[idx];
        ushort4 o;
        o.x = f2bf(f.x); o.y = f2bf(f.y); o.z = f2bf(f.z); o.w = f2bf(f.w);
        reinterpret_cast<ushort4*>(dst)[idx] = o;
    } else {
        int i   = blk - 16384;       // 0..4095
        int t   = threadIdx.x;
        int bh  = i >> 6;
        int kg  = i & 63;
        int d   = t & 63;
        int kci = t >> 6;
        int kc  = kg * 4 + kci;
        const float* src = cv_ + ((size_t)bh * NC_ + (size_t)kc * 8) * DH_ + d;
        union { uint4 u; unsigned short s[8]; } o;
#pragma unroll
        for (int j = 0; j < 8; j++) o.s[j] = f2bf(src[(size_t)j * DH_]);
        *reinterpret_cast<uint4*>(vt + ((size_t)bh * DH_ + d) * NC_ + (size_t)kc * 8) = o.u;
    }
}

#define LSTR 40

// ---------------- QKV GEMM (4096x1024)x(3072x1024)^T, 128x128 tile, dbuf LDS + scatter ----------------
// Double-buffered LDS: ds_write tile k+1 into buffer B while MFMAs consume A;
// ONE barrier per K-step (publishes B; A-overwrite safe since B-reads ended at
// the previous barrier). Reg prefetch 2 tiles ahead. Halves barrier drains vs R9.
__global__ __launch_bounds__(256, 3) void qkv_gemm_kernel(
    const unsigned short* __restrict__ xbf,
    const unsigned short* __restrict__ wbf,
    const float* __restrict__ bias,
    const int* __restrict__ uidx,
    unsigned short* __restrict__ qb,   // (B,H,NX,DH) scaled by 0.125*log2(e)
    unsigned short* __restrict__ kf,   // (B,H,NC,DH)
    unsigned short* __restrict__ vt)   // (B,H,DH,NC)
{
    __shared__ unsigned short As[2][128 * LSTR], Bs[2][128 * LSTR];
    __shared__ int jtab[128];
    int bn = blockIdx.x, bm = blockIdx.y;
    int w = threadIdx.x >> 6, l = threadIdx.x & 63;
    int quad = l >> 4, col = l & 15;
    int wr = w >> 1, wc = w & 1;
    int srow = w * 32 + (l >> 2), schk = (l & 3) * 8;

    const unsigned short* Ap = xbf + (size_t)(bm * 128 + srow) * C_ + schk;
    const unsigned short* Bp = wbf + (size_t)(bn * 128 + srow) * C_ + schk;

    f32x4 acc[4][4];
#pragma unroll
    for (int a = 0; a < 4; a++)
#pragma unroll
        for (int b = 0; b < 4; b++) acc[a][b] = (f32x4){0.f, 0.f, 0.f, 0.f};

    uint4 ar0, ar1, br0, br1;
#define LDREG(kk_)                                                       \
    {   int kk = (kk_) * 32;                                             \
        ar0 = *reinterpret_cast<const uint4*>(Ap + kk);                  \
        ar1 = *reinterpret_cast<const uint4*>(Ap + 16 * C_ + kk);        \
        br0 = *reinterpret_cast<const uint4*>(Bp + kk);                  \
        br1 = *reinterpret_cast<const uint4*>(Bp + 16 * C_ + kk);        \
    }
#define WRTILE(buf)                                                      \
    {   unsigned short* Aw = As[buf] + srow * LSTR + schk;               \
        unsigned short* Bw = Bs[buf] + srow * LSTR + schk;               \
        *reinterpret_cast<uint4*>(Aw)             = ar0;                 \
        *reinterpret_cast<uint4*>(Aw + 16 * LSTR) = ar1;                 \
        *reinterpret_cast<uint4*>(Bw)             = br0;                 \
        *reinterpret_cast<uint4*>(Bw + 16 * LSTR) = br1;                 \
    }

    LDREG(0);
    WRTILE(0);
    LDREG(1);
    __syncthreads();
#pragma unroll 1
    for (int it = 0; it < 32; it++) {
        int cur = it & 1;
        if (it < 31) WRTILE(1 - cur);            // tile it+1 (regs from it-1)
        if (it < 30) LDREG(it + 2);              // prefetch tile it+2
        bf16x8 af[4], bfr[4];
#pragma unroll
        for (int t = 0; t < 4; t++) af[t]  = ldfrag(&As[cur][(wr * 64 + t * 16 + col) * LSTR + quad * 8]);
#pragma unroll
        for (int t = 0; t < 4; t++) bfr[t] = ldfrag(&Bs[cur][(wc * 64 + t * 16 + col) * LSTR + quad * 8]);
#pragma unroll
        for (int mt = 0; mt < 4; mt++)
#pragma unroll
            for (int nt = 0; nt < 4; nt++)
                acc[mt][nt] = __builtin_amdgcn_mfma_f32_16x16x32_bf16(af[mt], bfr[nt], acc[mt][nt], 0, 0, 0);
        __syncthreads();                         // publish tile it+1; safe to overwrite cur next iter
    }
#undef LDREG
#undef WRTILE

    int part = bn >> 3;             // 0=q 1=k 2=v
    float bv[4];
#pragma unroll
    for (int nt = 0; nt < 4; nt++) bv[nt] = bias[bn * 128 + wc * 64 + nt * 16 + col];

    if (part <= 1) {
        int nl[4];
#pragma unroll
        for (int nt = 0; nt < 4; nt++) nl[nt] = (bn * 128 + wc * 64 + nt * 16 + col) & 1023;
        const float QS = 0.18033688011112042f;   // 0.125 * log2(e)
#pragma unroll
        for (int mt = 0; mt < 4; mt++)
#pragma unroll
            for (int r = 0; r < 4; r++) {
                int m = bm * 128 + wr * 64 + mt * 16 + quad * 4 + r;
                int b = m >> 10, i = m & 1023;
                int j = (part == 0) ? 0 : uidx[m];
#pragma unroll
                for (int nt = 0; nt < 4; nt++) {
                    int h = nl[nt] >> 6, d = nl[nt] & 63;
                    float v = acc[mt][nt][r] + bv[nt];
                    if (part == 0)
                        qb[((size_t)(b * H_ + h) * NX_ + i) * DH_ + d] = f2bf(v * QS);
                    else
                        kf[((size_t)(b * H_ + h) * NC_ + j) * DH_ + d] = f2bf(v);
                }
            }
    } else {
        // ---- V-part: LDS transpose + token-major scatter ----
        if (threadIdx.x < 128) jtab[threadIdx.x] = uidx[bm * 128 + threadIdx.x];
        __syncthreads();   // jtab ready; tile reads done
        int h = ((bn * 128 + wc * 64) & 1023) >> 6;
        int b = (bm * 128) >> 10;
        unsigned short* T = (wc == 0) ? &As[0][0] : &Bs[0][0];   // 64 x 72 bf16
        int jv = jtab[wr * 64 + l];
        unsigned short* vb2 = vt + ((size_t)(b * H_ + h) * 64) * NC_ + jv;
#pragma unroll 1
        for (int round = 0; round < 2; round++) {
            if (wr == round) {
#pragma unroll
                for (int nt = 0; nt < 4; nt++)
#pragma unroll
                    for (int mt = 0; mt < 4; mt++) {
                        uint2 pk;
                        pk.x = pk2(acc[mt][nt][0] + bv[nt], acc[mt][nt][1] + bv[nt]);
                        pk.y = pk2(acc[mt][nt][2] + bv[nt], acc[mt][nt][3] + bv[nt]);
                        *reinterpret_cast<uint2*>(&T[(nt * 16 + col) * 72 + mt * 16 + quad * 4]) = pk;
                    }
                asm volatile("s_waitcnt lgkmcnt(0)" ::: "memory");
#pragma unroll 1
                for (int d = 0; d < 64; d++)
                    vb2[(size_t)d * NC_] = T[d * 72 + l];   // lanes = 64 sorted tokens
            }
            __syncthreads();
        }
    }
}

// ---------------- flash attention: 32q/wave (qh,kh wave split), LDS-staged tiles ----------------
// (unchanged from R9 — frozen for attribution of the GEMM dbuf change)
#define PST 40
__global__ __launch_bounds__(256, 4) void attn_kernel(
    const unsigned short* __restrict__ qb,
    const unsigned short* __restrict__ kf,
    const unsigned short* __restrict__ vt,
    unsigned short* __restrict__ ao)          // (B,NX,C) bf16
{
    __shared__ __align__(16) char smem[20480 + 10240];
    unsigned short* Klo = (unsigned short*)smem;          // 64 x 40 (keys x dh0-31)
    unsigned short* Khi = Klo + 64 * LSTR;                // dh 32-63
    unsigned short* V0s = Khi + 64 * LSTR;                // V^T: dh x keys 0-31
    unsigned short* V1s = V0s + 64 * LSTR;                // keys 32-63
    unsigned short* Psh = (unsigned short*)(smem + 20480);// [wave][nt][16*PST]
    float* Om = (float*)smem;                             // aliases tiles after loop
    float* Lm = Om + 2 * 32 * 64;

    int id = blockIdx.x;
    int qt = (id >> 3) & 15;               // 0..15
    int bh = ((id >> 7) << 3) | (id & 7);  // 0..63, id%8 == bh%8 (XCD locality)
    int wave = threadIdx.x >> 6, lane = threadIdx.x & 63;
    int quad = lane >> 4, col = lane & 15;
    int qh = wave & 1;                     // query half (32 q)
    int kh = wave >> 1;                    // key half of each 64-key tile
    int srow = wave * 16 + (lane >> 2), schk = (lane & 3) * 8;

    const unsigned short* qrow0 = qb + ((size_t)bh * NX_ + qt * 64 + qh * 32 + col) * DH_;
    bf16x8 qfA[2], qfB[2];
    qfA[0] = ldfrag(qrow0 + quad * 8);
    qfB[0] = ldfrag(qrow0 + 32 + quad * 8);
    qfA[1] = ldfrag(qrow0 + 16 * DH_ + quad * 8);
    qfB[1] = ldfrag(qrow0 + 16 * DH_ + 32 + quad * 8);

    const unsigned short* Kp = kf + ((size_t)bh * NC_ + srow) * DH_ + schk;
    const unsigned short* Vp = vt + ((size_t)bh * DH_ + srow) * NC_ + schk;
    unsigned short* Kwl = Klo + srow * LSTR + schk;
    unsigned short* Kwh = Khi + srow * LSTR + schk;
    unsigned short* Vw0 = V0s + srow * LSTR + schk;
    unsigned short* Vw1 = V1s + srow * LSTR + schk;
    unsigned short* Pw0 = Psh + (wave * 2 + 0) * 16 * PST;
    unsigned short* Pw1 = Psh + (wave * 2 + 1) * 16 * PST;
    const unsigned short* Vs = kh ? V1s : V0s;
    int kq = kh * 32;

    f32x4 o[4][2];
#pragma unroll
    for (int m = 0; m < 4; m++)
#pragma unroll
        for (int n = 0; n < 2; n++) o[m][n] = (f32x4){0.f, 0.f, 0.f, 0.f};
    float l_i[2] = {0.f, 0.f};

    uint4 kr0, kr1, vr0, vr1;
#define LDREG(kb_)                                                        \
    {   kr0 = *reinterpret_cast<const uint4*>(Kp + (size_t)(kb_) * 64 * DH_);      \
        kr1 = *reinterpret_cast<const uint4*>(Kp + (size_t)(kb_) * 64 * DH_ + 32); \
        vr0 = *reinterpret_cast<const uint4*>(Vp + (kb_) * 64);           \
        vr1 = *reinterpret_cast<const uint4*>(Vp + (kb_) * 64 + 32);      \
    }
#define WRTILE()                                                          \
    {   *reinterpret_cast<uint4*>(Kwl) = kr0;                             \
        *reinterpret_cast<uint4*>(Kwh) = kr1;                             \
        *reinterpret_cast<uint4*>(Vw0) = vr0;                             \
        *reinterpret_cast<uint4*>(Vw1) = vr1;                             \
    }

    LDREG(0);
    WRTILE();
    LDREG(1);
    __syncthreads();

#pragma unroll 1
    for (int kb = 0; kb < 32; kb++) {
        f32x4 s[2][2];
#pragma unroll
        for (int mt = 0; mt < 2; mt++)
#pragma unroll
            for (int nt = 0; nt < 2; nt++) s[mt][nt] = (f32x4){0.f, 0.f, 0.f, 0.f};
#pragma unroll
        for (int mt = 0; mt < 2; mt++) {
            bf16x8 ka = ldfrag(&Klo[(kq + mt * 16 + col) * LSTR + quad * 8]);
            bf16x8 kb_ = ldfrag(&Khi[(kq + mt * 16 + col) * LSTR + quad * 8]);
#pragma unroll
            for (int nt = 0; nt < 2; nt++) {
                s[mt][nt] = __builtin_amdgcn_mfma_f32_16x16x32_bf16(ka,  qfA[nt], s[mt][nt], 0, 0, 0);
                s[mt][nt] = __builtin_amdgcn_mfma_f32_16x16x32_bf16(kb_, qfB[nt], s[mt][nt], 0, 0, 0);
            }
        }
        bf16x8 vfr[4];
#pragma unroll
        for (int t = 0; t < 4; t++) vfr[t] = ldfrag(&Vs[(t * 16 + col) * LSTR + quad * 8]);
#pragma unroll
        for (int nt = 0; nt < 2; nt++) {
            unsigned short* Pw = nt ? Pw1 : Pw0;
            float p0 = exp2f(s[0][nt][0]), p1 = exp2f(s[0][nt][1]);
            float p2 = exp2f(s[0][nt][2]), p3 = exp2f(s[0][nt][3]);
            float p4 = exp2f(s[1][nt][0]), p5 = exp2f(s[1][nt][1]);
            float p6 = exp2f(s[1][nt][2]), p7 = exp2f(s[1][nt][3]);
            l_i[nt] += ((p0 + p1) + (p2 + p3)) + ((p4 + p5) + (p6 + p7));
            uint2 w0; w0.x = pk2(p0, p1); w0.y = pk2(p2, p3);
            uint2 w1; w1.x = pk2(p4, p5); w1.y = pk2(p6, p7);
            *reinterpret_cast<uint2*>(&Pw[col * PST +      quad * 4]) = w0;
            *reinterpret_cast<uint2*>(&Pw[col * PST + 16 + quad * 4]) = w1;
        }
        asm volatile("" ::: "memory");
        {
            bf16x8 pf0 = ldfrag(&Pw0[col * PST + quad * 8]);
            bf16x8 pf1 = ldfrag(&Pw1[col * PST + quad * 8]);
#pragma unroll
            for (int mt = 0; mt < 4; mt++) {
                o[mt][0] = __builtin_amdgcn_mfma_f32_16x16x32_bf16(vfr[mt], pf0, o[mt][0], 0, 0, 0);
                o[mt][1] = __builtin_amdgcn_mfma_f32_16x16x32_bf16(vfr[mt], pf1, o[mt][1], 0, 0, 0);
            }
        }
        asm volatile("" ::: "memory");
        if (kb < 31) {
            __syncthreads();
            WRTILE();
            LDREG(kb + 2 < 31 ? kb + 2 : 31);
            __syncthreads();
        }
    }
#undef LDREG
#undef WRTILE

#pragma unroll
    for (int nt = 0; nt < 2; nt++) {
        l_i[nt] += __shfl_xor(l_i[nt], 16, 64);
        l_i[nt] += __shfl_xor(l_i[nt], 32, 64);
    }

    __syncthreads();   // tile reads done; smem reused as Om/Lm
    if (kh == 1) {
#pragma unroll
        for (int mt = 0; mt < 4; mt++)
#pragma unroll
            for (int nt = 0; nt < 2; nt++)
#pragma unroll
                for (int r = 0; r < 4; r++)
                    Om[(qh * 32 + (mt * 2 + nt) * 4 + r) * 64 + lane] = o[mt][nt][r];
        if (quad == 0) {
            Lm[(qh * 2 + 0) * 16 + col] = l_i[0];
            Lm[(qh * 2 + 1) * 16 + col] = l_i[1];
        }
    }
    __syncthreads();
    if (kh == 0) {
        float inv[2];
#pragma unroll
        for (int nt = 0; nt < 2; nt++)
            inv[nt] = 1.f / (l_i[nt] + Lm[(qh * 2 + nt) * 16 + col]);
        int b = bh >> 4, h = bh & 15;
#pragma unroll
        for (int mt = 0; mt < 4; mt++)
#pragma unroll
            for (int nt = 0; nt < 2; nt++) {
                int base = (qh * 32 + (mt * 2 + nt) * 4) * 64 + lane;
                float v0 = (o[mt][nt][0] + Om[base])       * inv[nt];
                float v1 = (o[mt][nt][1] + Om[base + 64])  * inv[nt];
                float v2 = (o[mt][nt][2] + Om[base + 128]) * inv[nt];
                float v3 = (o[mt][nt][3] + Om[base + 192]) * inv[nt];
                int q = qt * 64 + qh * 32 + nt * 16 + col;
                uint2 ov;
                ov.x = pk2(v0, v1);
                ov.y = pk2(v2, v3);
                *reinterpret_cast<uint2*>(ao + ((size_t)b * NX_ + q) * C_ +
                                          h * 64 + mt * 16 + quad * 4) = ov;
            }
    }
}

// ---------------- projection GEMM (4096x1024)x(1024x1024)^T, 128x64 tile, dbuf LDS ----------------
__global__ __launch_bounds__(256, 3) void proj_gemm_kernel(
    const unsigned short* __restrict__ abf,
    const unsigned short* __restrict__ wbf,
    const float* __restrict__ bias,
    float* __restrict__ out)
{
    __shared__ unsigned short As[2][128 * LSTR], Bs[2][64 * LSTR];
    int bn = blockIdx.x, bm = blockIdx.y;
    int w = threadIdx.x >> 6, l = threadIdx.x & 63;
    int quad = l >> 4, col = l & 15;
    int sarow = w * 32 + (l >> 2), sbrow = w * 16 + (l >> 2), schk = (l & 3) * 8;

    const unsigned short* Ap = abf + (size_t)(bm * 128 + sarow) * C_ + schk;
    const unsigned short* Bp = wbf + (size_t)(bn * 64 + sbrow) * C_ + schk;

    f32x4 acc[2][4];
#pragma unroll
    for (int a = 0; a < 2; a++)
#pragma unroll
        for (int b = 0; b < 4; b++) acc[a][b] = (f32x4){0.f, 0.f, 0.f, 0.f};

    uint4 ar0, ar1, br0;
#define LDREG(kk_)                                                       \
    {   int kk = (kk_) * 32;                                             \
        ar0 = *reinterpret_cast<const uint4*>(Ap + kk);                  \
        ar1 = *reinterpret_cast<const uint4*>(Ap + 16 * C_ + kk);        \
        br0 = *reinterpret_cast<const uint4*>(Bp + kk);                  \
    }
#define WRTILE(buf)                                                      \
    {   unsigned short* Aw = As[buf] + sarow * LSTR + schk;              \
        unsigned short* Bw = Bs[buf] + sbrow * LSTR + schk;              \
        *reinterpret_cast<uint4*>(Aw)             = ar0;                 \
        *reinterpret_cast<uint4*>(Aw + 16 * LSTR) = ar1;                 \
        *reinterpret_cast<uint4*>(Bw)             = br0;                 \
    }

    LDREG(0);
    WRTILE(0);
    LDREG(1);
    __syncthreads();
#pragma unroll 1
    for (int it = 0; it < 32; it++) {
        int cur = it & 1;
        if (it < 31) WRTILE(1 - cur);
        if (it < 30) LDREG(it + 2);
        bf16x8 af[2], bfr[4];
#pragma unroll
        for (int t = 0; t < 2; t++) af[t]  = ldfrag(&As[cur][(w * 32 + t * 16 + col) * LSTR + quad * 8]);
#pragma unroll
        for (int t = 0; t < 4; t++) bfr[t] = ldfrag(&Bs[cur][(t * 16 + col) * LSTR + quad * 8]);
#pragma unroll
        for (int mt = 0; mt < 2; mt++)
#pragma unroll
            for (int nt = 0; nt < 4; nt++)
                acc[mt][nt] = __builtin_amdgcn_mfma_f32_16x16x32_bf16(af[mt], bfr[nt], acc[mt][nt], 0, 0, 0);
        __syncthreads();
    }
#undef LDREG
#undef WRTILE

    float bv[4];
#pragma unroll
    for (int nt = 0; nt < 4; nt++) bv[nt] = bias[bn * 64 + nt * 16 + col];
#pragma unroll
    for (int mt = 0; mt < 2; mt++)
#pragma unroll
        for (int r = 0; r < 4; r++) {
            int m = bm * 128 + w * 32 + mt * 16 + quad * 4 + r;
#pragma unroll
            for (int nt = 0; nt < 4; nt++) {
                int n = bn * 64 + nt * 16 + col;
                out[(size_t)m * C_ + n] = acc[mt][nt][r] + bv[nt];
            }
        }
}

extern "C" void kernel_launch(void* const* d_in, const int* in_sizes, int n_in,
                              void* d_out, int out_size, void* d_ws, size_t ws_size,
                              hipStream_t stream) {
    const float* x      = (const float*)d_in[0];
    const int*   uidx   = (const int*)  d_in[1];
    const float* cachek = (const float*)d_in[2];
    const float* cachev = (const float*)d_in[3];
    const float* wqkv   = (const float*)d_in[4];
    const float* bqkv   = (const float*)d_in[5];
    const float* wproj  = (const float*)d_in[6];
    const float* bproj  = (const float*)d_in[7];
    float* out = (float*)d_out;

    char* ws = (char*)d_ws;
    unsigned short* xbf  = (unsigned short*)(ws);                       // 8 MB
    unsigned short* wqbf = (unsigned short*)(ws + (8ull  << 20));       // 6 MB
    unsigned short* wpbf = (unsigned short*)(ws + (14ull << 20));       // 2 MB
    unsigned short* qb   = (unsigned short*)(ws + (16ull << 20));       // 8 MB
    unsigned short* kfb  = (unsigned short*)(ws + (24ull << 20));       // 16 MB
    unsigned short* vtb  = (unsigned short*)(ws + (40ull << 20));       // 16 MB
    unsigned short* aob  = (unsigned short*)(ws + (56ull << 20));       // 8 MB

    cvt_all_kernel<<<20480, 256, 0, stream>>>(x, wqkv, wproj, cachek, cachev,
                                              xbf, wqbf, wpbf, kfb, vtb);
    qkv_gemm_kernel <<<dim3(24, 32), 256, 0, stream>>>(xbf, wqbf, bqkv, uidx, qb, kfb, vtb);
    attn_kernel     <<<1024, 256, 0, stream>>>(qb, kfb, vtb, aob);
    proj_gemm_kernel<<<dim3(16, 32), 256, 0, stream>>>(aob, wpbf, bproj, out);
}